// Round 1
// baseline (2737.650 us; speedup 1.0000x reference)
//
#include <hip/hip_runtime.h>
#include <stdint.h>

#define F_DIM 2048
#define H_DIM 4096
#define E_NUM 8
#define B_TOK 8192    // G*S tokens
#define T_ROWS 16384  // B_TOK * top_k
#define T_PAD  16512  // +128 pad rows for last partial M-block
#define NMB_MAX 136
#define BK 64

typedef __attribute__((ext_vector_type(8))) short bf16x8;   // 8 bf16 (4 VGPRs)
typedef __attribute__((ext_vector_type(4))) float f32x4;    // 4 fp32 acc

// ---------- helpers ----------
__device__ __forceinline__ unsigned short f2bf(float f) {
  union { float f; unsigned u; } v; v.f = f;
  unsigned u = v.u;
  unsigned r = u + 0x7fffu + ((u >> 16) & 1u);   // RNE
  return (unsigned short)(r >> 16);
}
__device__ __forceinline__ float bf2f(unsigned short u) {
  union { unsigned u; float f; } v; v.u = ((unsigned)u) << 16;
  return v.f;
}
__device__ __forceinline__ float gelu_tanh(float x) {
  // jax.nn.gelu approximate=True: 0.5x(1+tanh(sqrt(2/pi)(x+0.044715x^3)))
  float z = 0.7978845608028654f * (x + 0.044715f * x * x * x);
  float t = 1.0f - 2.0f / (__expf(2.0f * z) + 1.0f);
  return 0.5f * x * (1.0f + t);
}
__device__ __forceinline__ void gload16(const void* g, void* l) {
  // async 16B/lane global->LDS; LDS dest = wave-uniform base + lane*16
  __builtin_amdgcn_global_load_lds(
      (const __attribute__((address_space(1))) void*)g,
      (__attribute__((address_space(3))) void*)l, 16, 0, 0);
}

// ---------- 1. fp32 -> bf16 elementwise (w_gating) ----------
__global__ __launch_bounds__(256) void k_convert(const float* __restrict__ src,
                                                 unsigned short* __restrict__ dst,
                                                 long n4) {
  long i = (long)blockIdx.x * blockDim.x + threadIdx.x;
  long stride = (long)gridDim.x * blockDim.x;
  for (; i < n4; i += stride) {
    float4 v = ((const float4*)src)[i];
    ushort4 o;
    o.x = f2bf(v.x); o.y = f2bf(v.y); o.z = f2bf(v.z); o.w = f2bf(v.w);
    ((ushort4*)dst)[i] = o;
  }
}

// ---------- 2. router: RMSnorm -> logits -> softmax top-2 ----------
__global__ __launch_bounds__(256) void k_router(const float* __restrict__ x,
                                                const float* __restrict__ wr,
                                                const float* __restrict__ rscale,
                                                const float* __restrict__ pes,
                                                int* __restrict__ counts,
                                                int* __restrict__ meta_e,
                                                float* __restrict__ meta_w) {
  int t = blockIdx.x;
  int tid = threadIdx.x;
  const float* xr = x + (long)t * F_DIM;

  __shared__ float red[4];
  __shared__ float lg[4][8];

  // pass 1: sum of squares
  float ss = 0.f;
  for (int i = tid; i < F_DIM / 4; i += 256) {
    float4 v = ((const float4*)xr)[i];
    ss += v.x * v.x + v.y * v.y + v.z * v.z + v.w * v.w;
  }
  for (int o = 32; o >= 1; o >>= 1) ss += __shfl_down(ss, o, 64);
  if ((tid & 63) == 0) red[tid >> 6] = ss;
  __syncthreads();
  float sumsq = red[0] + red[1] + red[2] + red[3];
  float scale = rsqrtf(sumsq * (1.0f / F_DIM) + 1e-6f) * rsqrtf((float)F_DIM);

  // pass 2: logits (scalar scale applied after dot)
  float acc[8];
#pragma unroll
  for (int e = 0; e < 8; e++) acc[e] = 0.f;
  for (int f = tid; f < F_DIM; f += 256) {
    float v = xr[f] * rscale[f];
    const float* w = wr + f * 8;
#pragma unroll
    for (int e = 0; e < 8; e++) acc[e] += v * w[e];
  }
#pragma unroll
  for (int e = 0; e < 8; e++) {
    float a = acc[e];
    for (int o = 32; o >= 1; o >>= 1) a += __shfl_down(a, o, 64);
    if ((tid & 63) == 0) lg[tid >> 6][e] = a;
  }
  __syncthreads();
  if (tid == 0) {
    float l[8];
#pragma unroll
    for (int e = 0; e < 8; e++)
      l[e] = (lg[0][e] + lg[1][e] + lg[2][e] + lg[3][e]) * scale;
    int e0 = 0;
    for (int e = 1; e < 8; e++) if (l[e] > l[e0]) e0 = e;
    int e1 = (e0 == 0) ? 1 : 0;
    for (int e = 0; e < 8; e++) if (e != e0 && l[e] > l[e1]) e1 = e;
    // top-2 renormalized softmax (full-softmax denominator cancels)
    float p1 = __expf(l[e1] - l[e0]);
    float inv = 1.0f / (1.0f + p1);
    meta_e[2 * t] = e0; meta_e[2 * t + 1] = e1;
    meta_w[2 * t] = inv * pes[e0];
    meta_w[2 * t + 1] = p1 * inv * pes[e1];
    atomicAdd(&counts[e0], 1);
    atomicAdd(&counts[e1], 1);
  }
}

// ---------- 3. prefix sum + M-block schedule ----------
__global__ void k_sched(const int* __restrict__ counts, int* __restrict__ segoff,
                        int* __restrict__ nblocks, int4* __restrict__ sched) {
  if (threadIdx.x == 0 && blockIdx.x == 0) {
    int off = 0, nb = 0;
    for (int e = 0; e < 8; e++) {
      segoff[e] = off;
      int c = counts[e];
      int end = off + c;
      for (int i = 0; i < c; i += 128) {
        sched[nb].x = off + i; sched[nb].y = end; sched[nb].z = e; nb++;
      }
      off = end;
    }
    segoff[8] = off;
    *nblocks = nb;
    for (int b = nb; b < NMB_MAX; b++) { sched[b].x = 0; sched[b].y = 0; sched[b].z = 0; }
  }
}

// ---------- 4. scatter: assign sorted positions ----------
__global__ __launch_bounds__(256) void k_scatter(const int* __restrict__ meta_e,
                                                 const int* __restrict__ segoff,
                                                 int* __restrict__ fills,
                                                 int* __restrict__ meta_pos,
                                                 int* __restrict__ tok_of_row) {
  int t = blockIdx.x * blockDim.x + threadIdx.x;
  if (t >= B_TOK) return;
#pragma unroll
  for (int s = 0; s < 2; s++) {
    int e = meta_e[2 * t + s];
    int pos = segoff[e] + atomicAdd(&fills[e], 1);
    meta_pos[2 * t + s] = pos;
    tok_of_row[pos] = t;
  }
}

// ---------- 5. gather x rows -> bf16 sorted_x (+zero pad rows) ----------
__global__ __launch_bounds__(256) void k_gather(const float* __restrict__ x,
                                                const int* __restrict__ tok_of_row,
                                                unsigned short* __restrict__ sx) {
  int r = blockIdx.x;
  int tid = threadIdx.x;
  unsigned short* dst = sx + (long)r * F_DIM;
  if (r < T_ROWS) {
    const float4* src = (const float4*)(x + (long)tok_of_row[r] * F_DIM);
    for (int i = tid; i < F_DIM / 4; i += 256) {
      float4 v = src[i];
      ushort4 o;
      o.x = f2bf(v.x); o.y = f2bf(v.y); o.z = f2bf(v.z); o.w = f2bf(v.w);
      ((ushort4*)dst)[i] = o;
    }
  } else {
    ushort4 z = make_ushort4(0, 0, 0, 0);
    for (int i = tid; i < F_DIM / 4; i += 256) ((ushort4*)dst)[i] = z;
  }
}

// ---------- 6. GEMM1: sorted_x @ w_gate, fused gelu(g0)*g1 ----------
// block tile: 128 rows x (64 h-cols x 2 planes). waves own 32 rows x all 128 cols
// so each lane holds matching plane0/plane1 fragments for the gelu fuse.
__global__ __launch_bounds__(256) void k_gemm_gate(
    const unsigned short* __restrict__ sx,  // [T_PAD][F]
    const unsigned short* __restrict__ wg,  // [E][2H][F]  (B^T layout)
    const int4* __restrict__ sched, const int* __restrict__ nblocks,
    unsigned short* __restrict__ act)       // [T_PAD][H]
{
  int mb = blockIdx.y;
  if (mb >= *nblocks) return;
  int4 sc = sched[mb];
  int row0 = sc.x, row_end = sc.y, e = sc.z;
  int h0 = blockIdx.x * 64;

  __shared__ __align__(16) unsigned short sA[128 * BK];
  __shared__ __align__(16) unsigned short sB[128 * BK];

  int tid = threadIdx.x, lane = tid & 63, wv = tid >> 6;
  const unsigned short* Abase = sx + (long)row0 * F_DIM;
  const unsigned short* B0 = wg + ((long)e * 2 * H_DIM + h0) * F_DIM;
  const unsigned short* B1 = wg + ((long)e * 2 * H_DIM + H_DIM + h0) * F_DIM;

  f32x4 zero4 = {0.f, 0.f, 0.f, 0.f};
  f32x4 acc[2][8];
#pragma unroll
  for (int a = 0; a < 2; a++)
#pragma unroll
    for (int b = 0; b < 8; b++) acc[a][b] = zero4;

  int arow = lane >> 3;             // row within 8-row staging group
  int acol = (lane & 7) * 16;       // byte offset within 128B row

  for (int k0 = 0; k0 < F_DIM; k0 += BK) {
#pragma unroll
    for (int i = 0; i < 4; i++) {
      int j = wv * 4 + i;
      gload16((const char*)(Abase + (long)(8 * j + arow) * F_DIM + k0) + acol,
              (char*)sA + j * 1024);
      int nl = 8 * j + arow;
      const unsigned short* bb = (nl < 64) ? (B0 + (long)nl * F_DIM)
                                           : (B1 + (long)(nl - 64) * F_DIM);
      gload16((const char*)(bb + k0) + acol, (char*)sB + j * 1024);
    }
    __syncthreads();
#pragma unroll
    for (int kk = 0; kk < BK; kk += 32) {
      int lrow = lane & 15, lq = (lane >> 4) * 8;
      bf16x8 afr[2], bfr[8];
#pragma unroll
      for (int mt = 0; mt < 2; mt++)
        afr[mt] = *(const bf16x8*)&sA[(32 * wv + mt * 16 + lrow) * BK + kk + lq];
#pragma unroll
      for (int nt = 0; nt < 8; nt++)
        bfr[nt] = *(const bf16x8*)&sB[(nt * 16 + lrow) * BK + kk + lq];
#pragma unroll
      for (int mt = 0; mt < 2; mt++)
#pragma unroll
        for (int nt = 0; nt < 8; nt++)
          acc[mt][nt] = __builtin_amdgcn_mfma_f32_16x16x32_bf16(
              afr[mt], bfr[nt], acc[mt][nt], 0, 0, 0);
    }
    __syncthreads();
  }
  // epilogue: act[m][h] = gelu(plane0) * plane1   (masked by row_end)
  int lcol = lane & 15, lr4 = (lane >> 4) * 4;
#pragma unroll
  for (int mt = 0; mt < 2; mt++)
#pragma unroll
    for (int nt = 0; nt < 4; nt++) {
      f32x4 g0 = acc[mt][nt], g1 = acc[mt][nt + 4];
#pragma unroll
      for (int r = 0; r < 4; r++) {
        int m = row0 + 32 * wv + mt * 16 + lr4 + r;
        if (m < row_end) {
          int h = h0 + nt * 16 + lcol;
          act[(long)m * H_DIM + h] = f2bf(gelu_tanh(g0[r]) * g1[r]);
        }
      }
    }
}

// ---------- 7. transpose w_linear (E,H,F) fp32 -> (E,F,H) bf16 ----------
__global__ __launch_bounds__(256) void k_transpose(const float* __restrict__ wl,
                                                   unsigned short* __restrict__ wlt) {
  __shared__ float t[64 * 65];
  int e = blockIdx.z;
  int h0 = blockIdx.y * 64, f0 = blockIdx.x * 64;
  int tx = threadIdx.x & 63, ty = threadIdx.x >> 6;  // (64,4)
  const float* src = wl + ((long)e * H_DIM + h0) * F_DIM + f0;
#pragma unroll
  for (int r = 0; r < 16; r++) {
    int hl = r * 4 + ty;
    t[hl * 65 + tx] = src[(long)hl * F_DIM + tx];
  }
  __syncthreads();
  unsigned short* dst = wlt + ((long)e * F_DIM + f0) * H_DIM + h0;
#pragma unroll
  for (int r = 0; r < 16; r++) {
    int fl = r * 4 + ty;
    dst[(long)fl * H_DIM + tx] = f2bf(t[tx * 65 + fl]);
  }
}

// ---------- 8. GEMM2: act @ w_linear^T -> eout ----------
__global__ __launch_bounds__(256) void k_gemm_out(
    const unsigned short* __restrict__ act,  // [T_PAD][H]
    const unsigned short* __restrict__ wlt,  // [E][F][H]  (B^T layout)
    const int4* __restrict__ sched, const int* __restrict__ nblocks,
    unsigned short* __restrict__ eout)       // [T_ROWS][F]
{
  int mb = blockIdx.y;
  if (mb >= *nblocks) return;
  int4 sc = sched[mb];
  int row0 = sc.x, row_end = sc.y, e = sc.z;
  int n0 = blockIdx.x * 128;

  __shared__ __align__(16) unsigned short sA[128 * BK];
  __shared__ __align__(16) unsigned short sB[128 * BK];

  int tid = threadIdx.x, lane = tid & 63, wv = tid >> 6;
  int wm = wv >> 1, wn = wv & 1;
  const unsigned short* Abase = act + (long)row0 * H_DIM;
  const unsigned short* Bbase = wlt + ((long)e * F_DIM + n0) * H_DIM;

  f32x4 zero4 = {0.f, 0.f, 0.f, 0.f};
  f32x4 acc[4][4];
#pragma unroll
  for (int a = 0; a < 4; a++)
#pragma unroll
    for (int b = 0; b < 4; b++) acc[a][b] = zero4;

  int arow = lane >> 3, acol = (lane & 7) * 16;

  for (int k0 = 0; k0 < H_DIM; k0 += BK) {
#pragma unroll
    for (int i = 0; i < 4; i++) {
      int j = wv * 4 + i;
      gload16((const char*)(Abase + (long)(8 * j + arow) * H_DIM + k0) + acol,
              (char*)sA + j * 1024);
      gload16((const char*)(Bbase + (long)(8 * j + arow) * H_DIM + k0) + acol,
              (char*)sB + j * 1024);
    }
    __syncthreads();
#pragma unroll
    for (int kk = 0; kk < BK; kk += 32) {
      int lrow = lane & 15, lq = (lane >> 4) * 8;
      bf16x8 afr[4], bfr[4];
#pragma unroll
      for (int mt = 0; mt < 4; mt++)
        afr[mt] = *(const bf16x8*)&sA[(64 * wm + mt * 16 + lrow) * BK + kk + lq];
#pragma unroll
      for (int nt = 0; nt < 4; nt++)
        bfr[nt] = *(const bf16x8*)&sB[(64 * wn + nt * 16 + lrow) * BK + kk + lq];
#pragma unroll
      for (int mt = 0; mt < 4; mt++)
#pragma unroll
        for (int nt = 0; nt < 4; nt++)
          acc[mt][nt] = __builtin_amdgcn_mfma_f32_16x16x32_bf16(
              afr[mt], bfr[nt], acc[mt][nt], 0, 0, 0);
    }
    __syncthreads();
  }
  int lcol = lane & 15, lr4 = (lane >> 4) * 4;
#pragma unroll
  for (int mt = 0; mt < 4; mt++)
#pragma unroll
    for (int nt = 0; nt < 4; nt++) {
      f32x4 c = acc[mt][nt];
#pragma unroll
      for (int r = 0; r < 4; r++) {
        int m = row0 + 64 * wm + mt * 16 + lr4 + r;
        if (m < row_end) {
          int f = n0 + 64 * wn + nt * 16 + lcol;
          eout[(long)m * F_DIM + f] = f2bf(c[r]);
        }
      }
    }
}

// ---------- 9. combine: out = w0*eout[p0] + w1*eout[p1] ----------
__global__ __launch_bounds__(256) void k_combine(const unsigned short* __restrict__ eout,
                                                 const int* __restrict__ meta_pos,
                                                 const float* __restrict__ meta_w,
                                                 float* __restrict__ out) {
  int t = blockIdx.x;
  int tid = threadIdx.x;
  int p0 = meta_pos[2 * t], p1 = meta_pos[2 * t + 1];
  float w0 = meta_w[2 * t], w1 = meta_w[2 * t + 1];
  const ushort4* r0 = (const ushort4*)(eout + (long)p0 * F_DIM);
  const ushort4* r1 = (const ushort4*)(eout + (long)p1 * F_DIM);
  float4* o = (float4*)(out + (long)t * F_DIM);
  for (int i = tid; i < F_DIM / 4; i += 256) {
    ushort4 a = r0[i], b = r1[i];
    float4 v;
    v.x = w0 * bf2f(a.x) + w1 * bf2f(b.x);
    v.y = w0 * bf2f(a.y) + w1 * bf2f(b.y);
    v.z = w0 * bf2f(a.z) + w1 * bf2f(b.z);
    v.w = w0 * bf2f(a.w) + w1 * bf2f(b.w);
    o[i] = v;
  }
}

// ---------- workspace layout (bytes) ----------
#define WG_OFF   0L                            // 268,435,456 (E*2H*F*2); reused by wlt after GEMM1
#define SX_OFF   268435456L                    // sorted_x bf16 T_PAD*F*2; reused by eout after GEMM1
#define ACT_OFF  (268435456L + 67633152L)      // act bf16 T_PAD*H*2
#define CTRL_OFF (ACT_OFF + 135266304L)        // control/meta (~260 KB)

extern "C" void kernel_launch(void* const* d_in, const int* in_sizes, int n_in,
                              void* d_out, int out_size, void* d_ws, size_t ws_size,
                              hipStream_t stream) {
  const float* x    = (const float*)d_in[0];
  const float* wr   = (const float*)d_in[1];
  const float* wgat = (const float*)d_in[2];
  const float* wlin = (const float*)d_in[3];
  const float* pes  = (const float*)d_in[4];
  const float* rsc  = (const float*)d_in[5];
  float* out = (float*)d_out;

  char* ws = (char*)d_ws;
  unsigned short* wg_bf = (unsigned short*)(ws + WG_OFF);
  unsigned short* wlt   = (unsigned short*)(ws + WG_OFF);   // reuse after GEMM1
  unsigned short* sx    = (unsigned short*)(ws + SX_OFF);
  unsigned short* eout  = (unsigned short*)(ws + SX_OFF);   // reuse after GEMM1
  unsigned short* act   = (unsigned short*)(ws + ACT_OFF);
  char* ctrl = ws + CTRL_OFF;
  int*   counts   = (int*)(ctrl + 0);
  int*   fills    = (int*)(ctrl + 32);
  int*   segoff   = (int*)(ctrl + 64);
  int*   nblocks  = (int*)(ctrl + 128);
  int4*  sched    = (int4*)(ctrl + 256);
  int*   meta_e   = (int*)(ctrl + 4096);
  int*   meta_pos = (int*)(ctrl + 4096 + 65536);
  float* meta_w   = (float*)(ctrl + 4096 + 131072);
  int*   tok_of_row = (int*)(ctrl + 4096 + 196608);

  hipMemsetAsync(ctrl, 0, 64, stream);  // counts + fills

  k_convert<<<16384, 256, 0, stream>>>(wgat, wg_bf, (long)E_NUM * 2 * H_DIM * F_DIM / 4);
  k_router<<<B_TOK, 256, 0, stream>>>(x, wr, rsc, pes, counts, meta_e, meta_w);
  k_sched<<<1, 64, 0, stream>>>(counts, segoff, nblocks, sched);
  k_scatter<<<B_TOK / 256, 256, 0, stream>>>(meta_e, segoff, fills, meta_pos, tok_of_row);
  k_gather<<<T_PAD, 256, 0, stream>>>(x, tok_of_row, sx);
  k_gemm_gate<<<dim3(H_DIM / 64, NMB_MAX), 256, 0, stream>>>(sx, wg_bf, sched, nblocks, act);
  k_transpose<<<dim3(F_DIM / 64, H_DIM / 64, E_NUM), 256, 0, stream>>>(wlin, wlt);
  k_gemm_out<<<dim3(F_DIM / 128, NMB_MAX), 256, 0, stream>>>(act, wlt, sched, nblocks, eout);
  k_combine<<<B_TOK, 256, 0, stream>>>(eout, meta_pos, meta_w, out);
}

// Round 2
// 2445.542 us; speedup vs baseline: 1.1194x; 1.1194x over previous
//
#include <hip/hip_runtime.h>
#include <stdint.h>

#define F_DIM 2048
#define H_DIM 4096
#define E_NUM 8
#define B_TOK 8192    // G*S tokens
#define T_ROWS 16384  // B_TOK * top_k
#define T_PAD  16512  // +128 pad rows for last partial M-block
#define NMB_MAX 136
#define BK 64

typedef __attribute__((ext_vector_type(8))) short bf16x8;   // 8 bf16 (4 VGPRs)
typedef __attribute__((ext_vector_type(4))) float f32x4;    // 4 fp32 acc

// ---------- helpers ----------
__device__ __forceinline__ unsigned short f2bf(float f) {
  union { float f; unsigned u; } v; v.f = f;
  unsigned u = v.u;
  unsigned r = u + 0x7fffu + ((u >> 16) & 1u);   // RNE
  return (unsigned short)(r >> 16);
}
__device__ __forceinline__ float bf2f(unsigned short u) {
  union { unsigned u; float f; } v; v.u = ((unsigned)u) << 16;
  return v.f;
}
__device__ __forceinline__ float gelu_tanh(float x) {
  float z = 0.7978845608028654f * (x + 0.044715f * x * x * x);
  float t = 1.0f - 2.0f / (__expf(2.0f * z) + 1.0f);
  return 0.5f * x * (1.0f + t);
}
__device__ __forceinline__ void gload16(const void* g, void* l) {
  __builtin_amdgcn_global_load_lds(
      (const __attribute__((address_space(1))) void*)g,
      (__attribute__((address_space(3))) void*)l, 16, 0, 0);
}

// ---------- 1. fp32 -> bf16 elementwise (w_gating) ----------
__global__ __launch_bounds__(256) void k_convert(const float* __restrict__ src,
                                                 unsigned short* __restrict__ dst,
                                                 long n4) {
  long i = (long)blockIdx.x * blockDim.x + threadIdx.x;
  long stride = (long)gridDim.x * blockDim.x;
  for (; i < n4; i += stride) {
    float4 v = ((const float4*)src)[i];
    ushort4 o;
    o.x = f2bf(v.x); o.y = f2bf(v.y); o.z = f2bf(v.z); o.w = f2bf(v.w);
    ((ushort4*)dst)[i] = o;
  }
}

// ---------- 2. router: RMSnorm -> logits -> softmax top-2 ----------
__global__ __launch_bounds__(256) void k_router(const float* __restrict__ x,
                                                const float* __restrict__ wr,
                                                const float* __restrict__ rscale,
                                                const float* __restrict__ pes,
                                                int* __restrict__ counts,
                                                int* __restrict__ meta_e,
                                                float* __restrict__ meta_w) {
  int t = blockIdx.x;
  int tid = threadIdx.x;
  const float* xr = x + (long)t * F_DIM;

  __shared__ float red[4];
  __shared__ float lg[4][8];

  float ss = 0.f;
  for (int i = tid; i < F_DIM / 4; i += 256) {
    float4 v = ((const float4*)xr)[i];
    ss += v.x * v.x + v.y * v.y + v.z * v.z + v.w * v.w;
  }
  for (int o = 32; o >= 1; o >>= 1) ss += __shfl_down(ss, o, 64);
  if ((tid & 63) == 0) red[tid >> 6] = ss;
  __syncthreads();
  float sumsq = red[0] + red[1] + red[2] + red[3];
  float scale = rsqrtf(sumsq * (1.0f / F_DIM) + 1e-6f) * rsqrtf((float)F_DIM);

  float acc[8];
#pragma unroll
  for (int e = 0; e < 8; e++) acc[e] = 0.f;
  for (int f = tid; f < F_DIM; f += 256) {
    float v = xr[f] * rscale[f];
    const float* w = wr + f * 8;
#pragma unroll
    for (int e = 0; e < 8; e++) acc[e] += v * w[e];
  }
#pragma unroll
  for (int e = 0; e < 8; e++) {
    float a = acc[e];
    for (int o = 32; o >= 1; o >>= 1) a += __shfl_down(a, o, 64);
    if ((tid & 63) == 0) lg[tid >> 6][e] = a;
  }
  __syncthreads();
  if (tid == 0) {
    float l[8];
#pragma unroll
    for (int e = 0; e < 8; e++)
      l[e] = (lg[0][e] + lg[1][e] + lg[2][e] + lg[3][e]) * scale;
    int e0 = 0;
    for (int e = 1; e < 8; e++) if (l[e] > l[e0]) e0 = e;
    int e1 = (e0 == 0) ? 1 : 0;
    for (int e = 0; e < 8; e++) if (e != e0 && l[e] > l[e1]) e1 = e;
    float p1 = __expf(l[e1] - l[e0]);
    float inv = 1.0f / (1.0f + p1);
    meta_e[2 * t] = e0; meta_e[2 * t + 1] = e1;
    meta_w[2 * t] = inv * pes[e0];
    meta_w[2 * t + 1] = p1 * inv * pes[e1];
    atomicAdd(&counts[e0], 1);
    atomicAdd(&counts[e1], 1);
  }
}

// ---------- 3. prefix sum + M-block schedule ----------
__global__ void k_sched(const int* __restrict__ counts, int* __restrict__ segoff,
                        int* __restrict__ nblocks, int4* __restrict__ sched) {
  if (threadIdx.x == 0 && blockIdx.x == 0) {
    int off = 0, nb = 0;
    for (int e = 0; e < 8; e++) {
      segoff[e] = off;
      int c = counts[e];
      int end = off + c;
      for (int i = 0; i < c; i += 128) {
        sched[nb].x = off + i; sched[nb].y = end; sched[nb].z = e; nb++;
      }
      off = end;
    }
    segoff[8] = off;
    *nblocks = nb;
    for (int b = nb; b < NMB_MAX; b++) { sched[b].x = 0; sched[b].y = 0; sched[b].z = 0; }
  }
}

// ---------- 4. scatter: assign sorted positions ----------
__global__ __launch_bounds__(256) void k_scatter(const int* __restrict__ meta_e,
                                                 const int* __restrict__ segoff,
                                                 int* __restrict__ fills,
                                                 int* __restrict__ meta_pos,
                                                 int* __restrict__ tok_of_row) {
  int t = blockIdx.x * blockDim.x + threadIdx.x;
  if (t >= B_TOK) return;
#pragma unroll
  for (int s = 0; s < 2; s++) {
    int e = meta_e[2 * t + s];
    int pos = segoff[e] + atomicAdd(&fills[e], 1);
    meta_pos[2 * t + s] = pos;
    tok_of_row[pos] = t;
  }
}

// ---------- 5. gather x rows -> bf16 sorted_x (+zero pad rows) ----------
__global__ __launch_bounds__(256) void k_gather(const float* __restrict__ x,
                                                const int* __restrict__ tok_of_row,
                                                unsigned short* __restrict__ sx) {
  int r = blockIdx.x;
  int tid = threadIdx.x;
  unsigned short* dst = sx + (long)r * F_DIM;
  if (r < T_ROWS) {
    const float4* src = (const float4*)(x + (long)tok_of_row[r] * F_DIM);
    for (int i = tid; i < F_DIM / 4; i += 256) {
      float4 v = src[i];
      ushort4 o;
      o.x = f2bf(v.x); o.y = f2bf(v.y); o.z = f2bf(v.z); o.w = f2bf(v.w);
      ((ushort4*)dst)[i] = o;
    }
  } else {
    ushort4 z = make_ushort4(0, 0, 0, 0);
    for (int i = tid; i < F_DIM / 4; i += 256) ((ushort4*)dst)[i] = z;
  }
}

// ---------- 6. GEMM1: sorted_x @ w_gate, fused gelu(g0)*g1 ----------
// LDS granule XOR-swizzle: granule g (16B) of row r lives at position g^(r&7).
// Fetch side: lane loads global granule (lane&7)^(lane>>3) so linear
// global_load_lds (dest = base + lane*16) lands it at the swizzled slot.
__global__ __launch_bounds__(256) void k_gemm_gate(
    const unsigned short* __restrict__ sx,  // [T_PAD][F]
    const unsigned short* __restrict__ wg,  // [E][2H][F]  (B^T layout)
    const int4* __restrict__ sched, const int* __restrict__ nblocks,
    unsigned short* __restrict__ act)       // [T_PAD][H]
{
  int mb = blockIdx.y;
  if (mb >= *nblocks) return;
  int4 sc = sched[mb];
  int row0 = sc.x, row_end = sc.y, e = sc.z;
  int h0 = blockIdx.x * 64;

  __shared__ __align__(16) unsigned short sA[128 * BK];
  __shared__ __align__(16) unsigned short sB[128 * BK];

  int tid = threadIdx.x, lane = tid & 63, wv = tid >> 6;
  const unsigned short* Abase = sx + (long)row0 * F_DIM;
  const unsigned short* B0 = wg + ((long)e * 2 * H_DIM + h0) * F_DIM;
  const unsigned short* B1 = wg + ((long)e * 2 * H_DIM + H_DIM + h0) * F_DIM;

  f32x4 zero4 = {0.f, 0.f, 0.f, 0.f};
  f32x4 acc[2][8];
#pragma unroll
  for (int a = 0; a < 2; a++)
#pragma unroll
    for (int b = 0; b < 8; b++) acc[a][b] = zero4;

  int arow = lane >> 3;                         // row within 8-row group
  int acol = ((lane & 7) ^ arow) * 16;          // swizzled global granule

  for (int k0 = 0; k0 < F_DIM; k0 += BK) {
#pragma unroll
    for (int i = 0; i < 4; i++) {
      int j = wv * 4 + i;
      gload16((const char*)(Abase + (long)(8 * j + arow) * F_DIM + k0) + acol,
              (char*)sA + j * 1024);
      int nl = 8 * j + arow;
      const unsigned short* bb = (nl < 64) ? (B0 + (long)nl * F_DIM)
                                           : (B1 + (long)(nl - 64) * F_DIM);
      gload16((const char*)(bb + k0) + acol, (char*)sB + j * 1024);
    }
    __syncthreads();
#pragma unroll
    for (int kk = 0; kk < BK; kk += 32) {
      int lrow = lane & 15, q = lane >> 4;
      int gb = (kk >> 3) + q;                   // granule index 0..7
      bf16x8 afr[2], bfr[8];
#pragma unroll
      for (int mt = 0; mt < 2; mt++) {
        int r = 32 * wv + mt * 16 + lrow;
        afr[mt] = *(const bf16x8*)&sA[r * BK + ((gb ^ (r & 7)) << 3)];
      }
#pragma unroll
      for (int nt = 0; nt < 8; nt++) {
        int r = nt * 16 + lrow;
        bfr[nt] = *(const bf16x8*)&sB[r * BK + ((gb ^ (r & 7)) << 3)];
      }
#pragma unroll
      for (int mt = 0; mt < 2; mt++)
#pragma unroll
        for (int nt = 0; nt < 8; nt++)
          acc[mt][nt] = __builtin_amdgcn_mfma_f32_16x16x32_bf16(
              afr[mt], bfr[nt], acc[mt][nt], 0, 0, 0);
    }
    __syncthreads();
  }
  int lcol = lane & 15, lr4 = (lane >> 4) * 4;
#pragma unroll
  for (int mt = 0; mt < 2; mt++)
#pragma unroll
    for (int nt = 0; nt < 4; nt++) {
      f32x4 g0 = acc[mt][nt], g1 = acc[mt][nt + 4];
#pragma unroll
      for (int r = 0; r < 4; r++) {
        int m = row0 + 32 * wv + mt * 16 + lr4 + r;
        if (m < row_end) {
          int h = h0 + nt * 16 + lcol;
          act[(long)m * H_DIM + h] = f2bf(gelu_tanh(g0[r]) * g1[r]);
        }
      }
    }
}

// ---------- 7. transpose w_linear (E,H,F) fp32 -> (E,F,H) bf16 ----------
__global__ __launch_bounds__(256) void k_transpose(const float* __restrict__ wl,
                                                   unsigned short* __restrict__ wlt) {
  __shared__ float t[64 * 65];
  int e = blockIdx.z;
  int h0 = blockIdx.y * 64, f0 = blockIdx.x * 64;
  int tx = threadIdx.x & 63, ty = threadIdx.x >> 6;  // (64,4)
  const float* src = wl + ((long)e * H_DIM + h0) * F_DIM + f0;
#pragma unroll
  for (int r = 0; r < 16; r++) {
    int hl = r * 4 + ty;
    t[hl * 65 + tx] = src[(long)hl * F_DIM + tx];
  }
  __syncthreads();
  unsigned short* dst = wlt + ((long)e * F_DIM + f0) * H_DIM + h0;
#pragma unroll
  for (int r = 0; r < 16; r++) {
    int fl = r * 4 + ty;
    dst[(long)fl * H_DIM + tx] = f2bf(t[tx * 65 + fl]);
  }
}

// ---------- 8. GEMM2: act @ w_linear^T -> eout ----------
__global__ __launch_bounds__(256) void k_gemm_out(
    const unsigned short* __restrict__ act,  // [T_PAD][H]
    const unsigned short* __restrict__ wlt,  // [E][F][H]  (B^T layout)
    const int4* __restrict__ sched, const int* __restrict__ nblocks,
    unsigned short* __restrict__ eout)       // [T_ROWS][F]
{
  int mb = blockIdx.y;
  if (mb >= *nblocks) return;
  int4 sc = sched[mb];
  int row0 = sc.x, row_end = sc.y, e = sc.z;
  int n0 = blockIdx.x * 128;

  __shared__ __align__(16) unsigned short sA[128 * BK];
  __shared__ __align__(16) unsigned short sB[128 * BK];

  int tid = threadIdx.x, lane = tid & 63, wv = tid >> 6;
  int wm = wv >> 1, wn = wv & 1;
  const unsigned short* Abase = act + (long)row0 * H_DIM;
  const unsigned short* Bbase = wlt + ((long)e * F_DIM + n0) * H_DIM;

  f32x4 zero4 = {0.f, 0.f, 0.f, 0.f};
  f32x4 acc[4][4];
#pragma unroll
  for (int a = 0; a < 4; a++)
#pragma unroll
    for (int b = 0; b < 4; b++) acc[a][b] = zero4;

  int arow = lane >> 3;
  int acol = ((lane & 7) ^ arow) * 16;          // swizzled global granule

  for (int k0 = 0; k0 < H_DIM; k0 += BK) {
#pragma unroll
    for (int i = 0; i < 4; i++) {
      int j = wv * 4 + i;
      gload16((const char*)(Abase + (long)(8 * j + arow) * H_DIM + k0) + acol,
              (char*)sA + j * 1024);
      gload16((const char*)(Bbase + (long)(8 * j + arow) * H_DIM + k0) + acol,
              (char*)sB + j * 1024);
    }
    __syncthreads();
#pragma unroll
    for (int kk = 0; kk < BK; kk += 32) {
      int lrow = lane & 15, q = lane >> 4;
      int gb = (kk >> 3) + q;
      bf16x8 afr[4], bfr[4];
#pragma unroll
      for (int mt = 0; mt < 4; mt++) {
        int r = 64 * wm + mt * 16 + lrow;
        afr[mt] = *(const bf16x8*)&sA[r * BK + ((gb ^ (r & 7)) << 3)];
      }
#pragma unroll
      for (int nt = 0; nt < 4; nt++) {
        int r = 64 * wn + nt * 16 + lrow;
        bfr[nt] = *(const bf16x8*)&sB[r * BK + ((gb ^ (r & 7)) << 3)];
      }
#pragma unroll
      for (int mt = 0; mt < 4; mt++)
#pragma unroll
        for (int nt = 0; nt < 4; nt++)
          acc[mt][nt] = __builtin_amdgcn_mfma_f32_16x16x32_bf16(
              afr[mt], bfr[nt], acc[mt][nt], 0, 0, 0);
    }
    __syncthreads();
  }
  int lcol = lane & 15, lr4 = (lane >> 4) * 4;
#pragma unroll
  for (int mt = 0; mt < 4; mt++)
#pragma unroll
    for (int nt = 0; nt < 4; nt++) {
      f32x4 c = acc[mt][nt];
#pragma unroll
      for (int r = 0; r < 4; r++) {
        int m = row0 + 64 * wm + mt * 16 + lr4 + r;
        if (m < row_end) {
          int f = n0 + 64 * wn + nt * 16 + lcol;
          eout[(long)m * F_DIM + f] = f2bf(c[r]);
        }
      }
    }
}

// ---------- 9. combine: out = w0*eout[p0] + w1*eout[p1] ----------
__global__ __launch_bounds__(256) void k_combine(const unsigned short* __restrict__ eout,
                                                 const int* __restrict__ meta_pos,
                                                 const float* __restrict__ meta_w,
                                                 float* __restrict__ out) {
  int t = blockIdx.x;
  int tid = threadIdx.x;
  int p0 = meta_pos[2 * t], p1 = meta_pos[2 * t + 1];
  float w0 = meta_w[2 * t], w1 = meta_w[2 * t + 1];
  const ushort4* r0 = (const ushort4*)(eout + (long)p0 * F_DIM);
  const ushort4* r1 = (const ushort4*)(eout + (long)p1 * F_DIM);
  float4* o = (float4*)(out + (long)t * F_DIM);
  for (int i = tid; i < F_DIM / 4; i += 256) {
    ushort4 a = r0[i], b = r1[i];
    float4 v;
    v.x = w0 * bf2f(a.x) + w1 * bf2f(b.x);
    v.y = w0 * bf2f(a.y) + w1 * bf2f(b.y);
    v.z = w0 * bf2f(a.z) + w1 * bf2f(b.z);
    v.w = w0 * bf2f(a.w) + w1 * bf2f(b.w);
    o[i] = v;
  }
}

// ---------- workspace layout (bytes) ----------
#define WG_OFF   0L
#define SX_OFF   268435456L
#define ACT_OFF  (268435456L + 67633152L)
#define CTRL_OFF (ACT_OFF + 135266304L)

extern "C" void kernel_launch(void* const* d_in, const int* in_sizes, int n_in,
                              void* d_out, int out_size, void* d_ws, size_t ws_size,
                              hipStream_t stream) {
  const float* x    = (const float*)d_in[0];
  const float* wr   = (const float*)d_in[1];
  const float* wgat = (const float*)d_in[2];
  const float* wlin = (const float*)d_in[3];
  const float* pes  = (const float*)d_in[4];
  const float* rsc  = (const float*)d_in[5];
  float* out = (float*)d_out;

  char* ws = (char*)d_ws;
  unsigned short* wg_bf = (unsigned short*)(ws + WG_OFF);
  unsigned short* wlt   = (unsigned short*)(ws + WG_OFF);   // reuse after GEMM1
  unsigned short* sx    = (unsigned short*)(ws + SX_OFF);
  unsigned short* eout  = (unsigned short*)(ws + SX_OFF);   // reuse after GEMM1
  unsigned short* act   = (unsigned short*)(ws + ACT_OFF);
  char* ctrl = ws + CTRL_OFF;
  int*   counts   = (int*)(ctrl + 0);
  int*   fills    = (int*)(ctrl + 32);
  int*   segoff   = (int*)(ctrl + 64);
  int*   nblocks  = (int*)(ctrl + 128);
  int4*  sched    = (int4*)(ctrl + 256);
  int*   meta_e   = (int*)(ctrl + 4096);
  int*   meta_pos = (int*)(ctrl + 4096 + 65536);
  float* meta_w   = (float*)(ctrl + 4096 + 131072);
  int*   tok_of_row = (int*)(ctrl + 4096 + 196608);

  hipMemsetAsync(ctrl, 0, 64, stream);  // counts + fills

  k_convert<<<16384, 256, 0, stream>>>(wgat, wg_bf, (long)E_NUM * 2 * H_DIM * F_DIM / 4);
  k_router<<<B_TOK, 256, 0, stream>>>(x, wr, rsc, pes, counts, meta_e, meta_w);
  k_sched<<<1, 64, 0, stream>>>(counts, segoff, nblocks, sched);
  k_scatter<<<B_TOK / 256, 256, 0, stream>>>(meta_e, segoff, fills, meta_pos, tok_of_row);
  k_gather<<<T_PAD, 256, 0, stream>>>(x, tok_of_row, sx);
  k_gemm_gate<<<dim3(H_DIM / 64, NMB_MAX), 256, 0, stream>>>(sx, wg_bf, sched, nblocks, act);
  k_transpose<<<dim3(F_DIM / 64, H_DIM / 64, E_NUM), 256, 0, stream>>>(wlin, wlt);
  k_gemm_out<<<dim3(F_DIM / 128, NMB_MAX), 256, 0, stream>>>(act, wlt, sched, nblocks, eout);
  k_combine<<<B_TOK, 256, 0, stream>>>(eout, meta_pos, meta_w, out);
}